// Round 6
// baseline (27.561 us; speedup 1.0000x reference)
//
#include <hip/hip_runtime.h>

typedef short bf16x8 __attribute__((ext_vector_type(8)));
typedef float f32x4 __attribute__((ext_vector_type(4)));
typedef ushort u16x8 __attribute__((ext_vector_type(8)));

#define MFMA16(A, B, C) __builtin_amdgcn_mfma_f32_16x16x32_bf16((A), (B), (C), 0, 0, 0)

static __device__ __forceinline__ ushort f2bf(float f) {
    unsigned u = __builtin_bit_cast(unsigned, f);
    unsigned r = (u + 0x7FFFu + ((u >> 16) & 1u)) >> 16;
    return (ushort)r;
}
static __device__ __forceinline__ unsigned pk2(float a, float b) {
    return (unsigned)f2bf(a) | ((unsigned)f2bf(b) << 16);
}
static __device__ __forceinline__ bf16x8 ldg8(const ushort* p) {
    uint4 u = *(const uint4*)p;
    return __builtin_bit_cast(bf16x8, u);
}

// ---- workspace layout (bytes) ----
// kT : [2][24][32pad][512] bf16            @ 0        size 1572864
// v4 : [4][2][512][25][32pad] bf16         @ 1572864  size 6553600
// total 8126464   (Q is consumed directly from f32 by attn — no transpose copy)
#define OFF_KT 0
#define OFF_V4 1572864
#define WS_NEED 8126464

// Fused K/V prep (unchanged from R4 — best config):
//   blocks [0, 576)     : k -> kT bf16 [2][24][32pad][512] (pad cols unwritten:
//                         they only feed softmax-masked tap positions)
//   blocks [576, 2176)  : v -> v4 gather [4][2][512][25][32pad], full coverage
__global__ __launch_bounds__(256) void prep(const float* __restrict__ k,
                                            const float* __restrict__ v,
                                            ushort* __restrict__ kt,
                                            ushort* __restrict__ v4) {
    __shared__ float tile[32][33];
    int bid = blockIdx.x;

    if (bid < 576) {
        int b = bid / 288;
        int rem = bid % 288;
        int p0 = (rem / 16) * 32;
        int c0 = (rem % 16) * 32;
        int tx = threadIdx.x & 31, tw = threadIdx.x >> 5;
#pragma unroll
        for (int i = 0; i < 4; ++i) {
            int r = tw + i * 8;
            tile[r][tx] = k[(size_t)(b * 512 + c0 + r) * 576 + p0 + tx];
        }
        __syncthreads();
#pragma unroll
        for (int i = 0; i < 4; ++i) {
            int r = tw + i * 8;
            int pix = p0 + r;
            int kr = pix / 24, kc = pix % 24;
            kt[((size_t)(b * 24 + kr) * 32 + kc) * 512 + c0 + tx] = f2bf(tile[tx][r]);
        }
    } else {
        int tid = (bid - 576) * 256 + threadIdx.x;  // 409600 threads total
        int col0 = (tid & 3) * 8;
        int rowlin = tid >> 2;
        int kr = rowlin % 25;
        int c = (rowlin / 25) % 512;
        int b = (rowlin / (25 * 512)) & 1;
        int s = rowlin / (25 * 512 * 2);
        const float* src = v + (size_t)(b * 512 + c) * 576 + kr * 24;
        u16x8 w;
#pragma unroll
        for (int j = 0; j < 8; ++j) {
            int srcc = col0 + j + 2 * s;
            w[j] = (kr < 24 && srcc < 24) ? f2bf(src[srcc]) : (ushort)0;
        }
        *(u16x8*)&v4[(size_t)rowlin * 32 + col0] = w;
    }
}

// One wave per (2x8 pixel tile, head). 2304 blocks x 64 threads.
// R6: V-fragment loads hoisted to kernel start (issue-early, T14) so their
// latency hides under QK^T + softmax; s_setprio around MFMA clusters (T5).
__global__ __launch_bounds__(64) void attn(const float* __restrict__ q,
                                           const ushort* __restrict__ kt,
                                           const ushort* __restrict__ v4,
                                           float* __restrict__ out) {
    __shared__ __align__(16) unsigned Plds[16][84];  // [pixel][160 taps as bf16 pairs]

    int bid = blockIdx.x;
    int h = bid & 7;
    int t = bid >> 3;
    int tx = t % 6;
    int tyb = t / 6;  // 0..47
    int ty = tyb % 24;
    int b = tyb / 24;

    int l = threadIdx.x;
    int pix = l & 15, g = l >> 4;
    int px = pix & 7, py = pix >> 3;
    int y = ty * 2 + py, x = tx * 8 + px;

    int sr = min(max(ty - 4, 0), 15);            // shared row start (all 16 pixels)
    int sw0 = min(max(4 * tx - 4, 0), 15);       // col start of first pixel
    int swe = sw0 & ~1;                          // even base of col-union
    int sw = min(max((x >> 1) - 4, 0), 15);      // this pixel's col start
    int dx = sw - swe;                           // 0..4: valid tap cols = [dx, dx+8]
    int s2 = swe & 6, scopy = s2 >> 1, colbase = swe - s2;  // colbase in {0,8}

    // ---- issue-early: V fragments for the whole PV phase (addresses depend
    //      only on block coords; latency hides under q-gather/QK/softmax) ----
    bf16x8 vf[5][4];
#pragma unroll
    for (int ks = 0; ks < 5; ++ks) {
        int tap0 = ks * 32 + g * 8;
        int tr = tap0 >> 4, tc0 = tap0 & 15;
#pragma unroll
        for (int md = 0; md < 4; ++md) {
            int c = h * 64 + md * 16 + pix;
            vf[ks][md] = ldg8(v4 + ((size_t)((scopy * 2 + b) * 512 + c) * 25 + sr + tr) * 32 + colbase + tc0);
        }
    }

    // Q fragments (B-operand: col=pixel, k = channel within head), gathered
    // straight from q[b][c][y][x] (stride 2304 floats between channels).
    const float* qsrc = q + (size_t)(b * 512 + h * 64 + g * 8) * 2304 + y * 48 + x;
    float t0[8], t1[8];
#pragma unroll
    for (int j = 0; j < 8; ++j) t0[j] = qsrc[(size_t)j * 2304];
#pragma unroll
    for (int j = 0; j < 8; ++j) t1[j] = qsrc[(size_t)(j + 32) * 2304];
    bf16x8 q0, q1;
#pragma unroll
    for (int j = 0; j < 8; ++j) {
        q0[j] = (short)f2bf(t0[j]);
        q1[j] = (short)f2bf(t1[j]);
    }

    // QK^T (swapped): S^T[tap][pixel], 9 mtiles of 16 taps
    f32x4 sc[9];
    __builtin_amdgcn_s_setprio(1);
#pragma unroll
    for (int m = 0; m < 9; ++m) {
        int koff = (((b * 24 + sr + m) << 5) + swe + pix) * 512 + h * 64 + g * 8;
        bf16x8 k0 = ldg8(kt + koff), k1 = ldg8(kt + koff + 32);
        f32x4 a = {0.f, 0.f, 0.f, 0.f};
        a = MFMA16(k0, q0, a);
        a = MFMA16(k1, q1, a);
        sc[m] = a;
    }
    __builtin_amdgcn_s_setprio(0);

    // masked softmax over taps; lane holds tap cols tc = g*4+r for all 9 rows
    const float C2 = 0.18033688011112042f;  // 0.125 * log2(e)
    float mx = -3.0e38f;
#pragma unroll
    for (int r = 0; r < 4; ++r) {
        if ((unsigned)(g * 4 + r - dx) <= 8u) {
#pragma unroll
            for (int m = 0; m < 9; ++m) mx = fmaxf(mx, sc[m][r]);
        }
    }
    mx = fmaxf(mx, __shfl_xor(mx, 16));
    mx = fmaxf(mx, __shfl_xor(mx, 32));
    float sum = 0.f;
#pragma unroll
    for (int m = 0; m < 9; ++m) {
#pragma unroll
        for (int r = 0; r < 4; ++r) {
            bool valid = (unsigned)(g * 4 + r - dx) <= 8u;
            float p = valid ? exp2f((sc[m][r] - mx) * C2) : 0.f;
            sc[m][r] = p;
            sum += p;
        }
    }
    sum += __shfl_xor(sum, 16);
    sum += __shfl_xor(sum, 32);

    // P -> LDS (bf16), layout [pixel][tap] so PV B-frag reads are contiguous 16B
#pragma unroll
    for (int m = 0; m < 9; ++m) {
        uint2 w;
        w.x = pk2(sc[m][0], sc[m][1]);
        w.y = pk2(sc[m][2], sc[m][3]);
        *(uint2*)&Plds[pix][m * 8 + g * 2] = w;
    }
    *(uint2*)&Plds[pix][72 + g * 2] = make_uint2(0u, 0u);  // taps 144..159 = 0

    // PV (swapped): out^T[d][pixel] = V^T (A) x P^T (B), K = 160 taps
    f32x4 o[4] = {{0.f, 0.f, 0.f, 0.f}, {0.f, 0.f, 0.f, 0.f}, {0.f, 0.f, 0.f, 0.f}, {0.f, 0.f, 0.f, 0.f}};
    __builtin_amdgcn_s_setprio(1);
#pragma unroll
    for (int ks = 0; ks < 5; ++ks) {
        uint4 pw = *(const uint4*)&Plds[pix][ks * 16 + g * 4];
        bf16x8 pf = __builtin_bit_cast(bf16x8, pw);
#pragma unroll
        for (int md = 0; md < 4; ++md) {
            o[md] = MFMA16(vf[ks][md], pf, o[md]);
        }
    }
    __builtin_amdgcn_s_setprio(0);

    float invd = 1.0f / sum;
#pragma unroll
    for (int md = 0; md < 4; ++md) {
#pragma unroll
        for (int r = 0; r < 4; ++r) {
            int d = md * 16 + g * 4 + r;
            out[((size_t)(b * 512 + h * 64 + d) * 48 + y) * 48 + x] = o[md][r] * invd;
        }
    }
}

extern "C" void kernel_launch(void* const* d_in, const int* in_sizes, int n_in,
                              void* d_out, int out_size, void* d_ws, size_t ws_size,
                              hipStream_t stream) {
    const float* q = (const float*)d_in[0];
    const float* k = (const float*)d_in[1];
    const float* v = (const float*)d_in[2];
    float* out = (float*)d_out;
    char* ws = (char*)d_ws;
    if (ws_size < (size_t)WS_NEED) return;

    ushort* kt = (ushort*)(ws + OFF_KT);
    ushort* v4 = (ushort*)(ws + OFF_V4);

    prep<<<2176, 256, 0, stream>>>(k, v, kt, v4);
    attn<<<2304, 64, 0, stream>>>(q, kt, v4, out);
}

// Round 8
// 24.276 us; speedup vs baseline: 1.1353x; 1.1353x over previous
//
#include <hip/hip_runtime.h>
#include <hip/hip_cooperative_groups.h>

typedef short bf16x8 __attribute__((ext_vector_type(8)));
typedef float f32x4 __attribute__((ext_vector_type(4)));
typedef ushort u16x8 __attribute__((ext_vector_type(8)));

#define MFMA16(A, B, C) __builtin_amdgcn_mfma_f32_16x16x32_bf16((A), (B), (C), 0, 0, 0)

static __device__ __forceinline__ ushort f2bf(float f) {
    unsigned u = __builtin_bit_cast(unsigned, f);
    unsigned r = (u + 0x7FFFu + ((u >> 16) & 1u)) >> 16;
    return (ushort)r;
}
static __device__ __forceinline__ unsigned pk2(float a, float b) {
    return (unsigned)f2bf(a) | ((unsigned)f2bf(b) << 16);
}
static __device__ __forceinline__ bf16x8 ldg8(const ushort* p) {
    uint4 u = *(const uint4*)p;
    return __builtin_bit_cast(bf16x8, u);
}

// ---- workspace layout (bytes) ----
// kT : [2][24][32pad][512] bf16            @ 0        size 1572864
// v4 : [4][2][512][25][32pad] bf16         @ 1572864  size 6553600
#define OFF_KT 0
#define OFF_V4 1572864
#define WS_NEED 8126464

// ======== shared device helpers: tile geometry + attn body (R4-identical) ====
struct TileCtx {
    int h, tx, ty, b;
    int pix, g, y, x;
    int sr, swe, dx, scopy, colbase;
};

static __device__ __forceinline__ TileCtx make_ctx(int job, int l) {
    TileCtx c;
    c.h = job & 7;
    int t = job >> 3;
    c.tx = t % 6;
    int tyb = t / 6;
    c.ty = tyb % 24;
    c.b = tyb / 24;
    c.pix = l & 15;
    c.g = l >> 4;
    int px = c.pix & 7, py = c.pix >> 3;
    c.y = c.ty * 2 + py;
    c.x = c.tx * 8 + px;
    c.sr = min(max(c.ty - 4, 0), 15);
    int sw0 = min(max(4 * c.tx - 4, 0), 15);
    c.swe = sw0 & ~1;
    int sw = min(max((c.x >> 1) - 4, 0), 15);
    c.dx = sw - c.swe;
    int s2 = c.swe & 6;
    c.scopy = s2 >> 1;
    c.colbase = c.swe - s2;
    return c;
}

// q-gather: straight from q[b][c][y][x] (stride 2304 between channels)
static __device__ __forceinline__ void q_gather(const float* __restrict__ q,
                                                const TileCtx& c, bf16x8& q0, bf16x8& q1) {
    const float* qsrc = q + (size_t)(c.b * 512 + c.h * 64 + c.g * 8) * 2304 + c.y * 48 + c.x;
    float t0[8], t1[8];
#pragma unroll
    for (int j = 0; j < 8; ++j) t0[j] = qsrc[(size_t)j * 2304];
#pragma unroll
    for (int j = 0; j < 8; ++j) t1[j] = qsrc[(size_t)(j + 32) * 2304];
#pragma unroll
    for (int j = 0; j < 8; ++j) {
        q0[j] = (short)f2bf(t0[j]);
        q1[j] = (short)f2bf(t1[j]);
    }
}

// Full attn body given Q fragments (R4-identical arithmetic).
static __device__ __forceinline__ void attn_body(const TileCtx& c, bf16x8 q0, bf16x8 q1,
                                                 const ushort* __restrict__ kt,
                                                 const ushort* __restrict__ v4,
                                                 float* __restrict__ out,
                                                 unsigned (*Plds)[84]) {
    int pix = c.pix, g = c.g;
    // QK^T (swapped): S^T[tap][pixel], 9 mtiles of 16 taps
    f32x4 sc[9];
#pragma unroll
    for (int m = 0; m < 9; ++m) {
        int koff = (((c.b * 24 + c.sr + m) << 5) + c.swe + pix) * 512 + c.h * 64 + g * 8;
        bf16x8 k0 = ldg8(kt + koff), k1 = ldg8(kt + koff + 32);
        f32x4 a = {0.f, 0.f, 0.f, 0.f};
        a = MFMA16(k0, q0, a);
        a = MFMA16(k1, q1, a);
        sc[m] = a;
    }

    const float C2 = 0.18033688011112042f;  // 0.125 * log2(e)
    float mx = -3.0e38f;
#pragma unroll
    for (int r = 0; r < 4; ++r) {
        if ((unsigned)(g * 4 + r - c.dx) <= 8u) {
#pragma unroll
            for (int m = 0; m < 9; ++m) mx = fmaxf(mx, sc[m][r]);
        }
    }
    mx = fmaxf(mx, __shfl_xor(mx, 16));
    mx = fmaxf(mx, __shfl_xor(mx, 32));
    float sum = 0.f;
#pragma unroll
    for (int m = 0; m < 9; ++m) {
#pragma unroll
        for (int r = 0; r < 4; ++r) {
            bool valid = (unsigned)(g * 4 + r - c.dx) <= 8u;
            float p = valid ? exp2f((sc[m][r] - mx) * C2) : 0.f;
            sc[m][r] = p;
            sum += p;
        }
    }
    sum += __shfl_xor(sum, 16);
    sum += __shfl_xor(sum, 32);

#pragma unroll
    for (int m = 0; m < 9; ++m) {
        uint2 w;
        w.x = pk2(sc[m][0], sc[m][1]);
        w.y = pk2(sc[m][2], sc[m][3]);
        *(uint2*)&Plds[pix][m * 8 + g * 2] = w;
    }
    *(uint2*)&Plds[pix][72 + g * 2] = make_uint2(0u, 0u);  // taps 144..159 = 0

    f32x4 o[4] = {{0.f, 0.f, 0.f, 0.f}, {0.f, 0.f, 0.f, 0.f}, {0.f, 0.f, 0.f, 0.f}, {0.f, 0.f, 0.f, 0.f}};
#pragma unroll
    for (int ks = 0; ks < 5; ++ks) {
        uint4 pw = *(const uint4*)&Plds[pix][ks * 16 + g * 4];
        bf16x8 pf = __builtin_bit_cast(bf16x8, pw);
        int tap0 = ks * 32 + g * 8;
        int tr = tap0 >> 4, tc0 = tap0 & 15;
#pragma unroll
        for (int md = 0; md < 4; ++md) {
            int ch = c.h * 64 + md * 16 + pix;
            const ushort* vp = v4 + ((size_t)((c.scopy * 2 + c.b) * 512 + ch) * 25 + c.sr + tr) * 32 + c.colbase + tc0;
            o[md] = MFMA16(ldg8(vp), pf, o[md]);
        }
    }

    float invd = 1.0f / sum;
#pragma unroll
    for (int md = 0; md < 4; ++md) {
#pragma unroll
        for (int r = 0; r < 4; ++r) {
            int d = md * 16 + g * 4 + r;
            out[((size_t)(c.b * 512 + c.h * 64 + d) * 48 + c.y) * 48 + c.x] = o[md][r] * invd;
        }
    }
}

// ======== fallback path kernels (R4-identical) ========
__global__ __launch_bounds__(256) void prep(const float* __restrict__ k,
                                            const float* __restrict__ v,
                                            ushort* __restrict__ kt,
                                            ushort* __restrict__ v4) {
    __shared__ float tile[32][33];
    int bid = blockIdx.x;

    if (bid < 576) {
        int b = bid / 288;
        int rem = bid % 288;
        int p0 = (rem / 16) * 32;
        int c0 = (rem % 16) * 32;
        int tx = threadIdx.x & 31, tw = threadIdx.x >> 5;
#pragma unroll
        for (int i = 0; i < 4; ++i) {
            int r = tw + i * 8;
            tile[r][tx] = k[(size_t)(b * 512 + c0 + r) * 576 + p0 + tx];
        }
        __syncthreads();
#pragma unroll
        for (int i = 0; i < 4; ++i) {
            int r = tw + i * 8;
            int pix = p0 + r;
            int kr = pix / 24, kc = pix % 24;
            kt[((size_t)(b * 24 + kr) * 32 + kc) * 512 + c0 + tx] = f2bf(tile[tx][r]);
        }
    } else {
        int tid = (bid - 576) * 256 + threadIdx.x;  // 409600 threads total
        int col0 = (tid & 3) * 8;
        int rowlin = tid >> 2;
        int kr = rowlin % 25;
        int c = (rowlin / 25) % 512;
        int b = (rowlin / (25 * 512)) & 1;
        int s = rowlin / (25 * 512 * 2);
        const float* src = v + (size_t)(b * 512 + c) * 576 + kr * 24;
        u16x8 w;
#pragma unroll
        for (int j = 0; j < 8; ++j) {
            int srcc = col0 + j + 2 * s;
            w[j] = (kr < 24 && srcc < 24) ? f2bf(src[srcc]) : (ushort)0;
        }
        *(u16x8*)&v4[(size_t)rowlin * 32 + col0] = w;
    }
}

__global__ __launch_bounds__(64) void attn(const float* __restrict__ q,
                                           const ushort* __restrict__ kt,
                                           const ushort* __restrict__ v4,
                                           float* __restrict__ out) {
    __shared__ __align__(16) unsigned Plds[16][84];
    TileCtx c = make_ctx(blockIdx.x, threadIdx.x);
    bf16x8 q0, q1;
    q_gather(q, c, q0, q1);
    attn_body(c, q0, q1, kt, v4, out, Plds);
}

// ======== cooperative single-launch kernel ========
__global__ __launch_bounds__(64, 4) void fused(const float* __restrict__ q,
                                               const float* __restrict__ k,
                                               const float* __restrict__ v,
                                               ushort* __restrict__ kt,
                                               ushort* __restrict__ v4,
                                               float* __restrict__ out) {
    __shared__ __align__(16) unsigned Plds[16][84];

    int bid = blockIdx.x;
    int l = threadIdx.x;
    TileCtx c = make_ctx(bid, l);

    // phase 0: q-gather first; HBM latency hides under phase 1 + barrier
    bf16x8 q0, q1;
    q_gather(q, c, q0, q1);

    // phase 1: prep spread over all 147456 threads
    int tid = bid * 64 + l;
    {
        int c0 = (tid & 127) * 4;
        int pixlin = tid >> 7;
        int kb = pixlin / 576;
        int rem = pixlin % 576;
        int kr = rem / 24, kc = rem % 24;
        const float* kp = k + (size_t)(kb * 512 + c0) * 576 + kr * 24 + kc;
        ushort4 w;
        w.x = f2bf(kp[0]);
        w.y = f2bf(kp[576]);
        w.z = f2bf(kp[1152]);
        w.w = f2bf(kp[1728]);
        *(ushort4*)&kt[((size_t)(kb * 24 + kr) * 32 + kc) * 512 + c0] = w;
    }
#pragma unroll
    for (int i = 0; i < 3; ++i) {
        int gid = tid + i * 147456;
        if (gid < 409600) {
            int col0 = (gid & 3) * 8;
            int rowlin = gid >> 2;
            int kr = rowlin % 25;
            int ch = (rowlin / 25) % 512;
            int vb = (rowlin / (25 * 512)) & 1;
            int s = rowlin / (25 * 512 * 2);
            const float* src = v + (size_t)(vb * 512 + ch) * 576 + kr * 24;
            u16x8 w;
#pragma unroll
            for (int j = 0; j < 8; ++j) {
                int srcc = col0 + j + 2 * s;
                w[j] = (kr < 24 && srcc < 24) ? f2bf(src[srcc]) : (ushort)0;
            }
            *(u16x8*)&v4[(size_t)rowlin * 32 + col0] = w;
        }
    }

    __threadfence();
    cooperative_groups::this_grid().sync();
    __threadfence();

    attn_body(c, q0, q1, kt, v4, out, Plds);
}

extern "C" void kernel_launch(void* const* d_in, const int* in_sizes, int n_in,
                              void* d_out, int out_size, void* d_ws, size_t ws_size,
                              hipStream_t stream) {
    const float* q = (const float*)d_in[0];
    const float* k = (const float*)d_in[1];
    const float* v = (const float*)d_in[2];
    float* out = (float*)d_out;
    char* ws = (char*)d_ws;
    if (ws_size < (size_t)WS_NEED) return;

    ushort* kt = (ushort*)(ws + OFF_KT);
    ushort* v4 = (ushort*)(ws + OFF_V4);

    // Capacity pre-check (host-side queries only; capture-safe, deterministic).
    int dev = 0;
    (void)hipGetDevice(&dev);
    int numCU = 0;
    (void)hipDeviceGetAttribute(&numCU, hipDeviceAttributeMultiprocessorCount, dev);
    int maxBlocksPerCU = 0;
    (void)hipOccupancyMaxActiveBlocksPerMultiprocessor(&maxBlocksPerCU, (const void*)fused, 64, 0);

    bool coop_ok = (numCU > 0) && ((long)maxBlocksPerCU * numCU >= 2304);
    if (coop_ok) {
        void* args[] = {(void*)&q, (void*)&k, (void*)&v, (void*)&kt, (void*)&v4, (void*)&out};
        hipError_t rc = hipLaunchCooperativeKernel((const void*)fused, dim3(2304), dim3(64), args, 0, stream);
        if (rc == hipSuccess) return;
    }
    // Fallback: known-good R4 two-launch path.
    prep<<<2176, 256, 0, stream>>>(k, v, kt, v4);
    attn<<<2304, 64, 0, stream>>>(q, kt, v4, out);
}